// Round 11
// baseline (230.228 us; speedup 1.0000x reference)
//
#include <hip/hip_runtime.h>
#include <hip/hip_bf16.h>
#include <hip/hip_fp16.h>

#define DEV_INLINE __device__ __forceinline__

static DEV_INLINE float4 ld4(const float* p){ return *reinterpret_cast<const float4*>(p); }

#define GNUM 64
#define CHUNK 4096
#define MAXNB 1024   // bucket = dst>>7; N <= 65536 (u16 packing)
#define CAP 8192     // fixed per-bucket capacity (mean ~4096)

typedef _Float16 half8 __attribute__((ext_vector_type(8)));
typedef float floatx4 __attribute__((ext_vector_type(4)));

#define W1T_ELEMS (128*136)   // 17408
#define W2T_ELEMS (32*136)    // 4352

static DEV_INLINE int tile_of(int s, int TS){
    int t = 0;
    if (s >= TS)   t = 1;
    if (s >= 2*TS) t = 2;
    if (s >= 3*TS) t = 3;
    return t;
}

// ======================= single-pass bucketed edge build (+ fused weight prep) =======================
__global__ __launch_bounds__(256) void k_scatter(const int* __restrict__ src, const int* __restrict__ dst,
                                                 int E, int NB, int* __restrict__ bfill,
                                                 unsigned* __restrict__ ebuf,
                                                 const float* __restrict__ W1, const float* __restrict__ W2,
                                                 __half* __restrict__ w1t, __half* __restrict__ w2t, int EB){
    if ((int)blockIdx.x >= EB){   // weight-prep tail blocks
        int f = ((int)blockIdx.x - EB)*256 + threadIdx.x;
        if (f < W1T_ELEMS){
            int c = f/136, k = f - c*136;
            w1t[f] = (k<128) ? __float2half(W1[k*128+c]) : __float2half(0.f);
        } else {
            int f2 = f - W1T_ELEMS;
            if (f2 < W2T_ELEMS){
                int c = f2/136, k = f2 - c*136;
                w2t[f2] = (k<128) ? __float2half(W2[k*32+c]) : __float2half(0.f);
            }
        }
        return;
    }
    __shared__ int cnt[MAXNB];
    __shared__ int pfx[MAXNB];
    __shared__ int gbase[MAXNB];
    __shared__ unsigned stage[CHUNK];
    __shared__ int ws[4];
    int t = threadIdx.x; int base0 = blockIdx.x*CHUNK;
    int tot = E - base0; if (tot > CHUNK) tot = CHUNK;
    for (int i=t;i<NB;i+=256) cnt[i]=0;
    __syncthreads();
    unsigned v[16]; int rk[16];
    #pragma unroll
    for (int k=0;k<16;k++){
        int o = t + k*256;
        if (o < tot){
            int e = base0 + o;
            int s = src[e], d = dst[e];
            v[k] = (unsigned)s | ((unsigned)d<<16);
            rk[k] = atomicAdd(&cnt[d>>7], 1);
        } else { v[k]=0u; rk[k]=-1; }
    }
    __syncthreads();
    int i0 = t*4;
    int c0=(i0+0<NB)?cnt[i0+0]:0, c1=(i0+1<NB)?cnt[i0+1]:0;
    int c2=(i0+2<NB)?cnt[i0+2]:0, c3=(i0+3<NB)?cnt[i0+3]:0;
    int tsum=c0+c1+c2+c3;
    int lane=t&63, w=t>>6;
    int x=tsum;
    for (int off=1;off<64;off<<=1){ int yv=__shfl_up(x,off); if (lane>=off) x+=yv; }
    if (lane==63) ws[w]=x;
    __syncthreads();
    if (t==0){ int a=0; for (int i=0;i<4;i++){ int tmp=ws[i]; ws[i]=a; a+=tmp; } }
    __syncthreads();
    int ex = x - tsum + ws[w];
    if (i0+0<NB) pfx[i0+0]=ex; ex+=c0;
    if (i0+1<NB) pfx[i0+1]=ex; ex+=c1;
    if (i0+2<NB) pfx[i0+2]=ex; ex+=c2;
    if (i0+3<NB) pfx[i0+3]=ex;
    __syncthreads();
    for (int i=t;i<NB;i+=256){
        int c = cnt[i];
        if (c){
            int base = atomicAdd(&bfill[i], c);
            if (base > CAP - c) base = CAP - c;   // defensive clamp (never expected)
            gbase[i] = i*CAP + base;
        } else gbase[i] = 0;
    }
    __syncthreads();
    #pragma unroll
    for (int k=0;k<16;k++) if (rk[k]>=0){ int b = (int)(v[k]>>23); stage[pfx[b]+rk[k]] = v[k]; }
    __syncthreads();
    for (int j=t;j<tot;j+=256){
        unsigned u = stage[j];
        int b = (int)(u>>23);
        ebuf[gbase[b] + (j - pfx[b])] = u;
    }
}

// fused: per-(node,tile) count -> in-LDS prefix -> rs2 + dinv -> tile-ordered CSR (u16) fill
// block 0 threads 128..192 also compute graph boundaries (batch sorted).
__global__ __launch_bounds__(256) void k_bucket_finish(const unsigned* __restrict__ ebuf,
                                                       const int* __restrict__ bfill,
                                                       int2* __restrict__ rs2, unsigned short* __restrict__ csr,
                                                       float* __restrict__ dinv,
                                                       const int* __restrict__ batch, int* __restrict__ gstart,
                                                       int N, int TS){
    __shared__ int c2[512];
    __shared__ int rsl[512];
    __shared__ int ws[4];
    int b = blockIdx.x, t = threadIdx.x;
    for (int i=t;i<512;i+=256) c2[i]=0;
    if (b == 0 && t >= 128 && t < 128 + GNUM + 1){
        int g = t - 128;
        int lo = 0, hi = N;
        while (lo < hi){ int mid = (lo+hi)>>1; if (batch[mid] < g) lo = mid+1; else hi = mid; }
        gstart[g] = lo;
    }
    __syncthreads();
    int s0 = b*CAP;
    int cntB = bfill[b]; if (cntB > CAP) cntB = CAP;
    int s1 = s0 + cntB;
    for (int j = s0+t; j < s1; j += 256){
        unsigned u = ebuf[j];
        int key = (((u>>16)&127)<<2) | tile_of((int)(u & 0xffffu), TS);
        atomicAdd(&c2[key], 1);
    }
    __syncthreads();
    // exclusive scan over 512 keys (256 threads x 2)
    int i0 = t*2;
    int v0 = c2[i0], v1 = c2[i0+1];
    int tsum = v0 + v1;
    int lane = t & 63, w = t >> 6;
    int x = tsum;
    for (int off=1; off<64; off<<=1){
        int yv = __shfl_up(x, off);
        if (lane >= off) x += yv;
    }
    if (lane == 63) ws[w] = x;
    __syncthreads();
    if (t == 0){ int a=0; for (int i=0;i<4;i++){ int tmp=ws[i]; ws[i]=a; a+=tmp; } }
    __syncthreads();
    int ex = x - tsum + ws[w];
    rsl[i0]   = s0 + ex;
    rsl[i0+1] = s0 + ex + v0;
    __syncthreads();
    if (t < 128){
        int start = rsl[t<<2];
        int end   = (t < 127) ? rsl[(t+1)<<2] : s1;
        int node = (b<<7) + t;
        if (node < N){
            rs2[node] = make_int2(start, end);
            dinv[node] = rsqrtf((float)(end - start + 1));
        }
    }
    __syncthreads();
    for (int i=t;i<512;i+=256) c2[i]=0;
    __syncthreads();
    for (int j = s0+t; j < s1; j += 256){
        unsigned u = ebuf[j];
        int s = (int)(u & 0xffffu);
        int key = (((u>>16)&127)<<2) | tile_of(s, TS);
        int p = atomicAdd(&c2[key], 1);
        csr[rsl[key]+p] = (unsigned short)s;
    }
}

// ---------------- GEMM1 (MFMA fp16): y = (X @ W1) * dinv[row], fp16 out ----------------
__global__ __launch_bounds__(256) void k_gemm1(const float* __restrict__ X, const __half* __restrict__ w1t,
                                               const float* __restrict__ dinv, __half* __restrict__ yh, int N){
    __shared__ __half Wl[128*136];
    int t = threadIdx.x;
    if (blockIdx.x==0 && t < 32)
        reinterpret_cast<uint2*>(yh + (size_t)N*128)[t] = make_uint2(0u,0u);
    {
        const uint4* g = (const uint4*)w1t;
        uint4* l = (uint4*)Wl;
        for (int i = t; i < 2176; i += 256) l[i] = g[i];
    }
    __syncthreads();
    int wv = t>>6, lane = t&63;
    int r0 = blockIdx.x*64 + wv*16;
    if (r0 >= N) return;
    int lr = lane & 15, lg = lane >> 4;
    int r = r0 + lr;
    bool rok = r < N;
    const float* xrow = X + (size_t)(rok ? r : 0)*128;
    floatx4 acc[8];
    #pragma unroll
    for (int i=0;i<8;i++) acc[i] = (floatx4){0.f,0.f,0.f,0.f};
    #pragma unroll
    for (int ks=0; ks<4; ks++){
        int k0 = ks*32 + lg*8;
        float4 xa = ld4(xrow + k0);
        float4 xb = ld4(xrow + k0 + 4);
        half8 bfrag;
        bfrag[0]=(_Float16)xa.x; bfrag[1]=(_Float16)xa.y; bfrag[2]=(_Float16)xa.z; bfrag[3]=(_Float16)xa.w;
        bfrag[4]=(_Float16)xb.x; bfrag[5]=(_Float16)xb.y; bfrag[6]=(_Float16)xb.z; bfrag[7]=(_Float16)xb.w;
        #pragma unroll
        for (int ct=0; ct<8; ct++){
            half8 afrag = *reinterpret_cast<const half8*>(&Wl[(ct*16 + lr)*136 + k0]);
            acc[ct] = __builtin_amdgcn_mfma_f32_16x16x32_f16(afrag, bfrag, acc[ct], 0, 0, 0);
        }
    }
    if (rok){
        float dv = dinv[r];
        #pragma unroll
        for (int ct=0; ct<8; ct++){
            __half2 p0 = __floats2half2_rn(acc[ct][0]*dv, acc[ct][1]*dv);
            __half2 p1 = __floats2half2_rn(acc[ct][2]*dv, acc[ct][3]*dv);
            uint2 stv; stv.x = *(unsigned*)&p0; stv.y = *(unsigned*)&p1;
            *reinterpret_cast<uint2*>(&yh[(size_t)r*128 + ct*16 + lg*4]) = stv;
        }
    }
}

// ---------------- layer-1 aggregation: quarter-wave 16B gathers, stride-4 split (tile-phased) ----------------
__global__ void k_agg1(const __half* __restrict__ yh, const float* __restrict__ dinv,
                       const float* __restrict__ b1, const int2* __restrict__ rs2,
                       const unsigned short* __restrict__ csr, __half* __restrict__ h, int N){
    int wid = (int)((blockIdx.x * blockDim.x + threadIdx.x) >> 6);
    if (wid >= N) return;
    int lane = threadIdx.x & 63;
    int q = lane >> 4, ql = lane & 15;
    int2 se = rs2[wid];
    int beg = se.x, end = se.y;
    int len = end - beg;
    int qlen = (len + 3) >> 2;
    const char* yb = (const char*)yh;
    unsigned lofs = (unsigned)ql * 16u;
    float f0=0.f,f1=0.f,f2=0.f,f3=0.f,f4=0.f,f5=0.f,f6=0.f,f7=0.f;
    int iters = (qlen + 15) >> 4;
    for (int c=0;c<iters;c++){
        int o = c*16 + ql;
        int j = (o<<2) + q;                            // stride-4 interleave: tile-phase aligned
        int idx = (j < len) ? (int)csr[beg + j] : N;   // N = zero row
        int tmax = qlen - c*16; if (tmax > 16) tmax = 16;
        int nch = (tmax + 7) >> 3;
        __half2 a0 = __float2half2_rn(0.f), a1 = a0, a2 = a0, a3 = a0;
        for (int ch=0; ch<nch; ++ch){
            int tb = (q<<4) + ch*8;
            int s0 = __shfl(idx, tb+0);
            int s1 = __shfl(idx, tb+1);
            int s2 = __shfl(idx, tb+2);
            int s3 = __shfl(idx, tb+3);
            int s4 = __shfl(idx, tb+4);
            int s5 = __shfl(idx, tb+5);
            int s6 = __shfl(idx, tb+6);
            int s7 = __shfl(idx, tb+7);
            uint4 u0 = *(const uint4*)(yb + (((unsigned)s0<<8) + lofs));
            uint4 u1 = *(const uint4*)(yb + (((unsigned)s1<<8) + lofs));
            uint4 u2 = *(const uint4*)(yb + (((unsigned)s2<<8) + lofs));
            uint4 u3 = *(const uint4*)(yb + (((unsigned)s3<<8) + lofs));
            uint4 u4 = *(const uint4*)(yb + (((unsigned)s4<<8) + lofs));
            uint4 u5 = *(const uint4*)(yb + (((unsigned)s5<<8) + lofs));
            uint4 u6 = *(const uint4*)(yb + (((unsigned)s6<<8) + lofs));
            uint4 u7 = *(const uint4*)(yb + (((unsigned)s7<<8) + lofs));
            a0 = __hadd2(a0, *(__half2*)&u0.x); a1 = __hadd2(a1, *(__half2*)&u0.y);
            a2 = __hadd2(a2, *(__half2*)&u0.z); a3 = __hadd2(a3, *(__half2*)&u0.w);
            a0 = __hadd2(a0, *(__half2*)&u1.x); a1 = __hadd2(a1, *(__half2*)&u1.y);
            a2 = __hadd2(a2, *(__half2*)&u1.z); a3 = __hadd2(a3, *(__half2*)&u1.w);
            a0 = __hadd2(a0, *(__half2*)&u2.x); a1 = __hadd2(a1, *(__half2*)&u2.y);
            a2 = __hadd2(a2, *(__half2*)&u2.z); a3 = __hadd2(a3, *(__half2*)&u2.w);
            a0 = __hadd2(a0, *(__half2*)&u3.x); a1 = __hadd2(a1, *(__half2*)&u3.y);
            a2 = __hadd2(a2, *(__half2*)&u3.z); a3 = __hadd2(a3, *(__half2*)&u3.w);
            a0 = __hadd2(a0, *(__half2*)&u4.x); a1 = __hadd2(a1, *(__half2*)&u4.y);
            a2 = __hadd2(a2, *(__half2*)&u4.z); a3 = __hadd2(a3, *(__half2*)&u4.w);
            a0 = __hadd2(a0, *(__half2*)&u5.x); a1 = __hadd2(a1, *(__half2*)&u5.y);
            a2 = __hadd2(a2, *(__half2*)&u5.z); a3 = __hadd2(a3, *(__half2*)&u5.w);
            a0 = __hadd2(a0, *(__half2*)&u6.x); a1 = __hadd2(a1, *(__half2*)&u6.y);
            a2 = __hadd2(a2, *(__half2*)&u6.z); a3 = __hadd2(a3, *(__half2*)&u6.w);
            a0 = __hadd2(a0, *(__half2*)&u7.x); a1 = __hadd2(a1, *(__half2*)&u7.y);
            a2 = __hadd2(a2, *(__half2*)&u7.z); a3 = __hadd2(a3, *(__half2*)&u7.w);
        }
        float2 t0 = __half22float2(a0); f0 += t0.x; f1 += t0.y;
        float2 t1 = __half22float2(a1); f2 += t1.x; f3 += t1.y;
        float2 t2 = __half22float2(a2); f4 += t2.x; f5 += t2.y;
        float2 t3 = __half22float2(a3); f6 += t3.x; f7 += t3.y;
    }
    f0 += __shfl_xor(f0,16); f1 += __shfl_xor(f1,16); f2 += __shfl_xor(f2,16); f3 += __shfl_xor(f3,16);
    f4 += __shfl_xor(f4,16); f5 += __shfl_xor(f5,16); f6 += __shfl_xor(f6,16); f7 += __shfl_xor(f7,16);
    f0 += __shfl_xor(f0,32); f1 += __shfl_xor(f1,32); f2 += __shfl_xor(f2,32); f3 += __shfl_xor(f3,32);
    f4 += __shfl_xor(f4,32); f5 += __shfl_xor(f5,32); f6 += __shfl_xor(f6,32); f7 += __shfl_xor(f7,32);
    if (q == 0){
        uint4 su = *(const uint4*)(yb + (((unsigned)wid<<8) + lofs));   // self loop
        float2 s0 = __half22float2(*(__half2*)&su.x); f0 += s0.x; f1 += s0.y;
        float2 s1 = __half22float2(*(__half2*)&su.y); f2 += s1.x; f3 += s1.y;
        float2 s2 = __half22float2(*(__half2*)&su.z); f4 += s2.x; f5 += s2.y;
        float2 s3 = __half22float2(*(__half2*)&su.w); f6 += s3.x; f7 += s3.y;
        float dv = dinv[wid];
        float4 ba = ld4(&b1[ql*8]), bb = ld4(&b1[ql*8+4]);
        float o0 = dv*f0+ba.x, o1 = dv*f1+ba.y, o2 = dv*f2+ba.z, o3 = dv*f3+ba.w;
        float o4 = dv*f4+bb.x, o5 = dv*f5+bb.y, o6 = dv*f6+bb.z, o7 = dv*f7+bb.w;
        o0 = o0>0.f?o0:expm1f(o0); o1 = o1>0.f?o1:expm1f(o1);
        o2 = o2>0.f?o2:expm1f(o2); o3 = o3>0.f?o3:expm1f(o3);
        o4 = o4>0.f?o4:expm1f(o4); o5 = o5>0.f?o5:expm1f(o5);
        o6 = o6>0.f?o6:expm1f(o6); o7 = o7>0.f?o7:expm1f(o7);
        __half2 p0 = __floats2half2_rn(o0,o1), p1 = __floats2half2_rn(o2,o3);
        __half2 p2 = __floats2half2_rn(o4,o5), p3 = __floats2half2_rn(o6,o7);
        uint4 stv; stv.x=*(unsigned*)&p0; stv.y=*(unsigned*)&p1; stv.z=*(unsigned*)&p2; stv.w=*(unsigned*)&p3;
        *reinterpret_cast<uint4*>(&h[(size_t)wid*128 + ql*8]) = stv;
    }
}

// ---------------- fused mean-pool + MLP1 (one block per graph) ----------------
__global__ __launch_bounds__(256) void k_vn1(const __half* __restrict__ h, const int* __restrict__ gstart,
                                             const float* __restrict__ mW1, const float* __restrict__ mb1,
                                             __half* __restrict__ r1h){
    __shared__ float sums[4][128];
    __shared__ float msum[128];
    int g = blockIdx.x, t = threadIdx.x;
    int s0 = gstart[g], s1 = gstart[g+1];
    int c2i = t & 63, rg = t >> 6;
    const __half2* h2 = (const __half2*)h;
    float sx = 0.f, sy = 0.f;
    for (int r = s0+rg; r < s1; r += 4){
        float2 f = __half22float2(h2[(size_t)r*64 + c2i]);
        sx += f.x; sy += f.y;
    }
    sums[rg][2*c2i] = sx; sums[rg][2*c2i+1] = sy;
    __syncthreads();
    if (t < 128){
        float s = sums[0][t]+sums[1][t]+sums[2][t]+sums[3][t];
        int cnt = s1 - s0;
        msum[t] = s / (float)(cnt > 1 ? cnt : 1);
    }
    __syncthreads();
    if (t < 128){
        float acc = mb1[t];
        for (int k=0;k<128;k++) acc = fmaf(msum[k], mW1[k*128+t], acc);
        r1h[g*128+t] = __float2half(fmaxf(acc, 0.f));
    }
}

// ---------------- fused mean-pool + MLP2 (one block per graph) ----------------
__global__ __launch_bounds__(256) void k_vn2(const float* __restrict__ Z, const int* __restrict__ gstart,
                                             const float* __restrict__ mW2, const float* __restrict__ mb2,
                                             float* __restrict__ r2){
    __shared__ float sums[8][32];
    __shared__ float msum[32];
    int g = blockIdx.x, t = threadIdx.x;
    int s0 = gstart[g], s1 = gstart[g+1];
    int col = t & 31, rg = t >> 5;
    float s = 0.f;
    for (int r = s0+rg; r < s1; r += 8) s += Z[(size_t)r*32 + col];
    sums[rg][col] = s;
    __syncthreads();
    if (t < 32){
        float v = 0.f;
        #pragma unroll
        for (int i=0;i<8;i++) v += sums[i][t];
        int cnt = s1 - s0;
        msum[t] = v / (float)(cnt > 1 ? cnt : 1);
    }
    __syncthreads();
    if (t < 32){
        float acc = mb2[t];
        for (int k=0;k<32;k++) acc = fmaf(msum[k], mW2[k*32+t], acc);
        r2[g*32+t] = fmaxf(acc, 0.f);
    }
}

// ---------------- GEMM2 (MFMA fp16): y2 = ((h + r1h[batch]) @ W2) * dinv ----------------
__global__ __launch_bounds__(256) void k_gemm2(const __half* __restrict__ h, const __half* __restrict__ r1h,
                                               const int* __restrict__ batch, const __half* __restrict__ w2t,
                                               const float* __restrict__ dinv, __half* __restrict__ y2, int N){
    __shared__ __half Wl[32*136];
    int t = threadIdx.x;
    if (blockIdx.x==0 && t < 8)
        reinterpret_cast<uint2*>(y2 + (size_t)N*32)[t] = make_uint2(0u,0u);
    {
        const uint4* g = (const uint4*)w2t;
        uint4* l = (uint4*)Wl;
        for (int i = t; i < 544; i += 256) l[i] = g[i];
    }
    __syncthreads();
    int wv = t>>6, lane = t&63;
    int r0 = blockIdx.x*64 + wv*16;
    if (r0 >= N) return;
    int lr = lane & 15, lg = lane >> 4;
    int r = r0 + lr;
    bool rok = r < N;
    int rr = rok ? r : 0;
    const __half* hrow = h + (size_t)rr*128;
    const __half* vrow = r1h + (size_t)batch[rr]*128;
    floatx4 acc0 = (floatx4){0.f,0.f,0.f,0.f};
    floatx4 acc1 = (floatx4){0.f,0.f,0.f,0.f};
    #pragma unroll
    for (int ks=0; ks<4; ks++){
        int k0 = ks*32 + lg*8;
        uint4 hu = *reinterpret_cast<const uint4*>(hrow + k0);
        uint4 vu = *reinterpret_cast<const uint4*>(vrow + k0);
        __half2 b0 = __hadd2(*(__half2*)&hu.x, *(__half2*)&vu.x);
        __half2 b1_ = __hadd2(*(__half2*)&hu.y, *(__half2*)&vu.y);
        __half2 b2_ = __hadd2(*(__half2*)&hu.z, *(__half2*)&vu.z);
        __half2 b3_ = __hadd2(*(__half2*)&hu.w, *(__half2*)&vu.w);
        uint4 bu; bu.x=*(unsigned*)&b0; bu.y=*(unsigned*)&b1_; bu.z=*(unsigned*)&b2_; bu.w=*(unsigned*)&b3_;
        half8 bfrag = *reinterpret_cast<half8*>(&bu);
        half8 a0 = *reinterpret_cast<const half8*>(&Wl[(0*16 + lr)*136 + k0]);
        half8 a1 = *reinterpret_cast<const half8*>(&Wl[(1*16 + lr)*136 + k0]);
        acc0 = __builtin_amdgcn_mfma_f32_16x16x32_f16(a0, bfrag, acc0, 0, 0, 0);
        acc1 = __builtin_amdgcn_mfma_f32_16x16x32_f16(a1, bfrag, acc1, 0, 0, 0);
    }
    if (rok){
        float dv = dinv[r];
        {
            __half2 p0 = __floats2half2_rn(acc0[0]*dv, acc0[1]*dv);
            __half2 p1 = __floats2half2_rn(acc0[2]*dv, acc0[3]*dv);
            uint2 stv; stv.x = *(unsigned*)&p0; stv.y = *(unsigned*)&p1;
            *reinterpret_cast<uint2*>(&y2[(size_t)r*32 + 0 + lg*4]) = stv;
        }
        {
            __half2 p0 = __floats2half2_rn(acc1[0]*dv, acc1[1]*dv);
            __half2 p1 = __floats2half2_rn(acc1[2]*dv, acc1[3]*dv);
            uint2 stv; stv.x = *(unsigned*)&p0; stv.y = *(unsigned*)&p1;
            *reinterpret_cast<uint2*>(&y2[(size_t)r*32 + 16 + lg*4]) = stv;
        }
    }
}

// ---------------- layer-2 aggregation: octet-wave 8B gathers, stride-8 split (tile-phased) ----------------
__global__ void k_agg2h(const __half* __restrict__ y2, const float* __restrict__ dinv,
                        const float* __restrict__ b2, const int2* __restrict__ rs2,
                        const unsigned short* __restrict__ csr, float* __restrict__ Z, int N){
    int wid = (int)((blockIdx.x*blockDim.x + threadIdx.x) >> 6);
    if (wid >= N) return;
    int lane = threadIdx.x & 63;
    int o8 = lane >> 3, ol = lane & 7;
    int2 se = rs2[wid];
    int beg = se.x, end = se.y, len = end-beg;
    int olen = (len + 7) >> 3;
    const char* yb = (const char*)y2;
    unsigned lofs = (unsigned)ol * 8u;
    float f0=0.f, f1=0.f, f2=0.f, f3=0.f;
    int iters = (olen + 7) >> 3;
    for (int c=0;c<iters;c++){
        int o = c*8 + ol;
        int j = (o<<3) + o8;                           // stride-8 interleave
        int idx = (j < len) ? (int)csr[beg + j] : N;
        int tb = o8<<3;
        int s0 = __shfl(idx, tb+0);
        int s1 = __shfl(idx, tb+1);
        int s2 = __shfl(idx, tb+2);
        int s3 = __shfl(idx, tb+3);
        int s4 = __shfl(idx, tb+4);
        int s5 = __shfl(idx, tb+5);
        int s6 = __shfl(idx, tb+6);
        int s7 = __shfl(idx, tb+7);
        uint2 u0 = *(const uint2*)(yb + (((unsigned)s0<<6) + lofs));
        uint2 u1 = *(const uint2*)(yb + (((unsigned)s1<<6) + lofs));
        uint2 u2 = *(const uint2*)(yb + (((unsigned)s2<<6) + lofs));
        uint2 u3 = *(const uint2*)(yb + (((unsigned)s3<<6) + lofs));
        uint2 u4 = *(const uint2*)(yb + (((unsigned)s4<<6) + lofs));
        uint2 u5 = *(const uint2*)(yb + (((unsigned)s5<<6) + lofs));
        uint2 u6 = *(const uint2*)(yb + (((unsigned)s6<<6) + lofs));
        uint2 u7 = *(const uint2*)(yb + (((unsigned)s7<<6) + lofs));
        __half2 a0 = __float2half2_rn(0.f), a1 = a0;
        a0 = __hadd2(a0, *(__half2*)&u0.x); a1 = __hadd2(a1, *(__half2*)&u0.y);
        a0 = __hadd2(a0, *(__half2*)&u1.x); a1 = __hadd2(a1, *(__half2*)&u1.y);
        a0 = __hadd2(a0, *(__half2*)&u2.x); a1 = __hadd2(a1, *(__half2*)&u2.y);
        a0 = __hadd2(a0, *(__half2*)&u3.x); a1 = __hadd2(a1, *(__half2*)&u3.y);
        a0 = __hadd2(a0, *(__half2*)&u4.x); a1 = __hadd2(a1, *(__half2*)&u4.y);
        a0 = __hadd2(a0, *(__half2*)&u5.x); a1 = __hadd2(a1, *(__half2*)&u5.y);
        a0 = __hadd2(a0, *(__half2*)&u6.x); a1 = __hadd2(a1, *(__half2*)&u6.y);
        a0 = __hadd2(a0, *(__half2*)&u7.x); a1 = __hadd2(a1, *(__half2*)&u7.y);
        float2 t0 = __half22float2(a0); f0 += t0.x; f1 += t0.y;
        float2 t1 = __half22float2(a1); f2 += t1.x; f3 += t1.y;
    }
    f0 += __shfl_xor(f0,8);  f1 += __shfl_xor(f1,8);  f2 += __shfl_xor(f2,8);  f3 += __shfl_xor(f3,8);
    f0 += __shfl_xor(f0,16); f1 += __shfl_xor(f1,16); f2 += __shfl_xor(f2,16); f3 += __shfl_xor(f3,16);
    f0 += __shfl_xor(f0,32); f1 += __shfl_xor(f1,32); f2 += __shfl_xor(f2,32); f3 += __shfl_xor(f3,32);
    if (o8 == 0){
        uint2 su = *(const uint2*)(yb + (((unsigned)wid<<6) + lofs));   // self loop
        float2 s0 = __half22float2(*(__half2*)&su.x); f0 += s0.x; f1 += s0.y;
        float2 s1 = __half22float2(*(__half2*)&su.y); f2 += s1.x; f3 += s1.y;
        float dv = dinv[wid];
        float4 bb = ld4(&b2[ol*4]);
        float4 outv;
        outv.x = dv*f0 + bb.x; outv.y = dv*f1 + bb.y;
        outv.z = dv*f2 + bb.z; outv.w = dv*f3 + bb.w;
        *reinterpret_cast<float4*>(&Z[(size_t)wid*32 + ol*4]) = outv;
    }
}

// ---------------- + virtual node + softmax (in-place on d_out) ----------------
__global__ void k_softmax(float* __restrict__ Z, const float* __restrict__ r2,
                          const int* __restrict__ batch, int N){
    int r = blockIdx.x*8 + (threadIdx.x>>5);
    int c = threadIdx.x & 31;
    if (r >= N) return;
    float z = Z[(size_t)r*32+c] + r2[batch[r]*32 + c];
    float m = z;
    #pragma unroll
    for (int off=16; off>=1; off>>=1) m = fmaxf(m, __shfl_xor(m, off));
    float e = expf(z - m);
    float s = e;
    #pragma unroll
    for (int off=16; off>=1; off>>=1) s += __shfl_xor(s, off);
    Z[(size_t)r*32+c] = e / s;
}

extern "C" void kernel_launch(void* const* d_in, const int* in_sizes, int n_in,
                              void* d_out, int out_size, void* d_ws, size_t ws_size,
                              hipStream_t stream){
    const float* X   = (const float*)d_in[0];
    const float* W1  = (const float*)d_in[1];
    const float* b1  = (const float*)d_in[2];
    const float* W2  = (const float*)d_in[3];
    const float* b2  = (const float*)d_in[4];
    const float* mW1 = (const float*)d_in[5];
    const float* mb1 = (const float*)d_in[6];
    const float* mW2 = (const float*)d_in[7];
    const float* mb2 = (const float*)d_in[8];
    const int*   ei  = (const int*)d_in[9];
    const int*   batch = (const int*)d_in[10];
    int N = in_sizes[0] / 128;
    int E = in_sizes[9] / 2;
    const int* src = ei;
    const int* dst = ei + E;
    float* Zout = (float*)d_out;

    char* wsp = (char*)d_ws;
    size_t off = 0;
    auto alloc = [&](size_t bytes)->char*{
        char* p = wsp + off; off += (bytes + 255) & ~(size_t)255; return p;
    };
    // zero zone
    int*   bfill = (int*)  alloc((size_t)MAXNB*4);
    size_t zero_bytes = off;
    // rest
    int NB = (N + 127) >> 7;            // 391
    int2*  rs2   = (int2*) alloc((size_t)N*8);
    int*   gstart= (int*)  alloc((GNUM+1)*4);
    unsigned* ebuf = (unsigned*)alloc((size_t)NB*CAP*4);
    unsigned short* csr = (unsigned short*)alloc((size_t)NB*CAP*2);
    float* dinvp = (float*)alloc((size_t)N*4);
    __half* w1t  = (__half*)alloc((size_t)W1T_ELEMS*2);
    __half* w2t  = (__half*)alloc((size_t)W2T_ELEMS*2);
    __half* yh   = (__half*)alloc((size_t)(N+1)*128*2);   // +1: zero row
    __half* h    = (__half*)alloc((size_t)N*128*2);
    __half* y2h  = (__half*)alloc((size_t)(N+1)*32*2);    // +1: zero row
    __half* r1buf= (__half*)alloc((size_t)GNUM*128*2);
    float* r2buf = (float*)alloc((size_t)GNUM*32*4);
    (void)ws_size; (void)n_in; (void)out_size;

    hipMemsetAsync(d_ws, 0, zero_bytes, stream);

    int EB = (E + CHUNK-1) / CHUNK;     // 391
    int PREP = (W1T_ELEMS + W2T_ELEMS + 255)/256;   // 85
    int TS = (N + 3)/4;                 // 12500

    k_scatter      <<<EB + PREP, 256, 0, stream>>>(src, dst, E, NB, bfill, ebuf, W1, W2, w1t, w2t, EB);
    k_bucket_finish<<<NB, 256, 0, stream>>>(ebuf, bfill, rs2, csr, dinvp, batch, gstart, N, TS);

    k_gemm1 <<<(N+63)/64, 256, 0, stream>>>(X, w1t, dinvp, yh, N);
    k_agg1  <<<(N+3)/4, 256, 0, stream>>>(yh, dinvp, b1, rs2, csr, h, N);

    k_vn1   <<<GNUM, 256, 0, stream>>>(h, gstart, mW1, mb1, r1buf);

    k_gemm2 <<<(N+63)/64, 256, 0, stream>>>(h, r1buf, batch, w2t, dinvp, y2h, N);
    k_agg2h <<<(N+3)/4, 256, 0, stream>>>(y2h, dinvp, b2, rs2, csr, Zout, N);

    k_vn2   <<<GNUM, 256, 0, stream>>>(Zout, gstart, mW2, mb2, r2buf);
    k_softmax<<<(N+7)/8, 256, 0, stream>>>(Zout, r2buf, batch, N);
}

// Round 12
// 212.991 us; speedup vs baseline: 1.0809x; 1.0809x over previous
//
#include <hip/hip_runtime.h>
#include <hip/hip_bf16.h>
#include <hip/hip_fp16.h>

#define DEV_INLINE __device__ __forceinline__

static DEV_INLINE float4 ld4(const float* p){ return *reinterpret_cast<const float4*>(p); }

#define GNUM 64
#define CHUNK 4096
#define MAXNB 1024   // bucket = dst>>7; N <= 65536 (u16 packing)
#define CAP 8192     // fixed per-bucket capacity (mean ~4096)

typedef _Float16 half8 __attribute__((ext_vector_type(8)));
typedef float floatx4 __attribute__((ext_vector_type(4)));

#define W1T_ELEMS (128*136)   // 17408
#define W2T_ELEMS (32*136)    // 4352

static DEV_INLINE int tile_of(int s, int TS){
    int t = 0;
    if (s >= TS)   t = 1;
    if (s >= 2*TS) t = 2;
    if (s >= 3*TS) t = 3;
    return t;
}

// ======================= single-pass bucketed edge build (+ fused weight prep) =======================
__global__ __launch_bounds__(256) void k_scatter(const int* __restrict__ src, const int* __restrict__ dst,
                                                 int E, int NB, int* __restrict__ bfill,
                                                 unsigned* __restrict__ ebuf,
                                                 const float* __restrict__ W1, const float* __restrict__ W2,
                                                 __half* __restrict__ w1t, __half* __restrict__ w2t, int EB){
    if ((int)blockIdx.x >= EB){   // weight-prep tail blocks
        int f = ((int)blockIdx.x - EB)*256 + threadIdx.x;
        if (f < W1T_ELEMS){
            int c = f/136, k = f - c*136;
            w1t[f] = (k<128) ? __float2half(W1[k*128+c]) : __float2half(0.f);
        } else {
            int f2 = f - W1T_ELEMS;
            if (f2 < W2T_ELEMS){
                int c = f2/136, k = f2 - c*136;
                w2t[f2] = (k<128) ? __float2half(W2[k*32+c]) : __float2half(0.f);
            }
        }
        return;
    }
    __shared__ int cnt[MAXNB];
    __shared__ int pfx[MAXNB];
    __shared__ int gbase[MAXNB];
    __shared__ unsigned stage[CHUNK];
    __shared__ int ws[4];
    int t = threadIdx.x; int base0 = blockIdx.x*CHUNK;
    int tot = E - base0; if (tot > CHUNK) tot = CHUNK;
    for (int i=t;i<NB;i+=256) cnt[i]=0;
    __syncthreads();
    unsigned v[16]; int rk[16];
    #pragma unroll
    for (int k=0;k<16;k++){
        int o = t + k*256;
        if (o < tot){
            int e = base0 + o;
            int s = src[e], d = dst[e];
            v[k] = (unsigned)s | ((unsigned)d<<16);
            rk[k] = atomicAdd(&cnt[d>>7], 1);
        } else { v[k]=0u; rk[k]=-1; }
    }
    __syncthreads();
    int i0 = t*4;
    int c0=(i0+0<NB)?cnt[i0+0]:0, c1=(i0+1<NB)?cnt[i0+1]:0;
    int c2=(i0+2<NB)?cnt[i0+2]:0, c3=(i0+3<NB)?cnt[i0+3]:0;
    int tsum=c0+c1+c2+c3;
    int lane=t&63, w=t>>6;
    int x=tsum;
    for (int off=1;off<64;off<<=1){ int yv=__shfl_up(x,off); if (lane>=off) x+=yv; }
    if (lane==63) ws[w]=x;
    __syncthreads();
    if (t==0){ int a=0; for (int i=0;i<4;i++){ int tmp=ws[i]; ws[i]=a; a+=tmp; } }
    __syncthreads();
    int ex = x - tsum + ws[w];
    if (i0+0<NB) pfx[i0+0]=ex; ex+=c0;
    if (i0+1<NB) pfx[i0+1]=ex; ex+=c1;
    if (i0+2<NB) pfx[i0+2]=ex; ex+=c2;
    if (i0+3<NB) pfx[i0+3]=ex;
    __syncthreads();
    for (int i=t;i<NB;i+=256){
        int c = cnt[i];
        if (c){
            int base = atomicAdd(&bfill[i], c);
            if (base > CAP - c) base = CAP - c;   // defensive clamp (never expected)
            gbase[i] = i*CAP + base;
        } else gbase[i] = 0;
    }
    __syncthreads();
    #pragma unroll
    for (int k=0;k<16;k++) if (rk[k]>=0){ int b = (int)(v[k]>>23); stage[pfx[b]+rk[k]] = v[k]; }
    __syncthreads();
    for (int j=t;j<tot;j+=256){
        unsigned u = stage[j];
        int b = (int)(u>>23);
        ebuf[gbase[b] + (j - pfx[b])] = u;
    }
}

// fused: per-(node,tile) count -> in-LDS prefix -> rs2 + dinv -> tile-ordered CSR (u16) fill
__global__ __launch_bounds__(256) void k_bucket_finish(const unsigned* __restrict__ ebuf,
                                                       const int* __restrict__ bfill,
                                                       int2* __restrict__ rs2, unsigned short* __restrict__ csr,
                                                       float* __restrict__ dinv,
                                                       const int* __restrict__ batch, int* __restrict__ gstart,
                                                       int N, int TS){
    __shared__ int c2[512];
    __shared__ int rsl[512];
    __shared__ int ws[4];
    int b = blockIdx.x, t = threadIdx.x;
    for (int i=t;i<512;i+=256) c2[i]=0;
    if (b == 0 && t >= 128 && t < 128 + GNUM + 1){
        int g = t - 128;
        int lo = 0, hi = N;
        while (lo < hi){ int mid = (lo+hi)>>1; if (batch[mid] < g) lo = mid+1; else hi = mid; }
        gstart[g] = lo;
    }
    __syncthreads();
    int s0 = b*CAP;
    int cntB = bfill[b]; if (cntB > CAP) cntB = CAP;
    int s1 = s0 + cntB;
    for (int j = s0+t; j < s1; j += 256){
        unsigned u = ebuf[j];
        int key = (((u>>16)&127)<<2) | tile_of((int)(u & 0xffffu), TS);
        atomicAdd(&c2[key], 1);
    }
    __syncthreads();
    int i0 = t*2;
    int v0 = c2[i0], v1 = c2[i0+1];
    int tsum = v0 + v1;
    int lane = t & 63, w = t >> 6;
    int x = tsum;
    for (int off=1; off<64; off<<=1){
        int yv = __shfl_up(x, off);
        if (lane >= off) x += yv;
    }
    if (lane == 63) ws[w] = x;
    __syncthreads();
    if (t == 0){ int a=0; for (int i=0;i<4;i++){ int tmp=ws[i]; ws[i]=a; a+=tmp; } }
    __syncthreads();
    int ex = x - tsum + ws[w];
    rsl[i0]   = s0 + ex;
    rsl[i0+1] = s0 + ex + v0;
    __syncthreads();
    if (t < 128){
        int start = rsl[t<<2];
        int end   = (t < 127) ? rsl[(t+1)<<2] : s1;
        int node = (b<<7) + t;
        if (node < N){
            rs2[node] = make_int2(start, end);
            dinv[node] = rsqrtf((float)(end - start + 1));
        }
    }
    __syncthreads();
    for (int i=t;i<512;i+=256) c2[i]=0;
    __syncthreads();
    for (int j = s0+t; j < s1; j += 256){
        unsigned u = ebuf[j];
        int s = (int)(u & 0xffffu);
        int key = (((u>>16)&127)<<2) | tile_of(s, TS);
        int p = atomicAdd(&c2[key], 1);
        csr[rsl[key]+p] = (unsigned short)s;
    }
}

// ---------------- GEMM1 (MFMA fp16): y = (X @ W1) * dinv[row], fp16 out ----------------
__global__ __launch_bounds__(256) void k_gemm1(const float* __restrict__ X, const __half* __restrict__ w1t,
                                               const float* __restrict__ dinv, __half* __restrict__ yh, int N){
    __shared__ __half Wl[128*136];
    int t = threadIdx.x;
    if (blockIdx.x==0 && t < 32)
        reinterpret_cast<uint2*>(yh + (size_t)N*128)[t] = make_uint2(0u,0u);
    {
        const uint4* g = (const uint4*)w1t;
        uint4* l = (uint4*)Wl;
        for (int i = t; i < 2176; i += 256) l[i] = g[i];
    }
    __syncthreads();
    int wv = t>>6, lane = t&63;
    int r0 = blockIdx.x*64 + wv*16;
    if (r0 >= N) return;
    int lr = lane & 15, lg = lane >> 4;
    int r = r0 + lr;
    bool rok = r < N;
    const float* xrow = X + (size_t)(rok ? r : 0)*128;
    floatx4 acc[8];
    #pragma unroll
    for (int i=0;i<8;i++) acc[i] = (floatx4){0.f,0.f,0.f,0.f};
    #pragma unroll
    for (int ks=0; ks<4; ks++){
        int k0 = ks*32 + lg*8;
        float4 xa = ld4(xrow + k0);
        float4 xb = ld4(xrow + k0 + 4);
        half8 bfrag;
        bfrag[0]=(_Float16)xa.x; bfrag[1]=(_Float16)xa.y; bfrag[2]=(_Float16)xa.z; bfrag[3]=(_Float16)xa.w;
        bfrag[4]=(_Float16)xb.x; bfrag[5]=(_Float16)xb.y; bfrag[6]=(_Float16)xb.z; bfrag[7]=(_Float16)xb.w;
        #pragma unroll
        for (int ct=0; ct<8; ct++){
            half8 afrag = *reinterpret_cast<const half8*>(&Wl[(ct*16 + lr)*136 + k0]);
            acc[ct] = __builtin_amdgcn_mfma_f32_16x16x32_f16(afrag, bfrag, acc[ct], 0, 0, 0);
        }
    }
    if (rok){
        float dv = dinv[r];
        #pragma unroll
        for (int ct=0; ct<8; ct++){
            __half2 p0 = __floats2half2_rn(acc[ct][0]*dv, acc[ct][1]*dv);
            __half2 p1 = __floats2half2_rn(acc[ct][2]*dv, acc[ct][3]*dv);
            uint2 stv; stv.x = *(unsigned*)&p0; stv.y = *(unsigned*)&p1;
            *reinterpret_cast<uint2*>(&yh[(size_t)r*128 + ct*16 + lg*4]) = stv;
        }
    }
}

// ---------------- layer-1 aggregation: quarter-wave 16B gathers, stride-4 split (tile-phased) ----------------
__global__ void k_agg1(const __half* __restrict__ yh, const float* __restrict__ dinv,
                       const float* __restrict__ b1, const int2* __restrict__ rs2,
                       const unsigned short* __restrict__ csr, __half* __restrict__ h, int N){
    int wid = (int)((blockIdx.x * blockDim.x + threadIdx.x) >> 6);
    if (wid >= N) return;
    int lane = threadIdx.x & 63;
    int q = lane >> 4, ql = lane & 15;
    int2 se = rs2[wid];
    int beg = se.x, end = se.y;
    int len = end - beg;
    int qlen = (len + 3) >> 2;
    const char* yb = (const char*)yh;
    unsigned lofs = (unsigned)ql * 16u;
    float f0=0.f,f1=0.f,f2=0.f,f3=0.f,f4=0.f,f5=0.f,f6=0.f,f7=0.f;
    int iters = (qlen + 15) >> 4;
    for (int c=0;c<iters;c++){
        int o = c*16 + ql;
        int j = (o<<2) + q;                            // stride-4 interleave: tile-phase aligned
        int idx = (j < len) ? (int)csr[beg + j] : N;   // N = zero row
        int tmax = qlen - c*16; if (tmax > 16) tmax = 16;
        int nch = (tmax + 7) >> 3;
        __half2 a0 = __float2half2_rn(0.f), a1 = a0, a2 = a0, a3 = a0;
        for (int ch=0; ch<nch; ++ch){
            int tb = (q<<4) + ch*8;
            int s0 = __shfl(idx, tb+0);
            int s1 = __shfl(idx, tb+1);
            int s2 = __shfl(idx, tb+2);
            int s3 = __shfl(idx, tb+3);
            int s4 = __shfl(idx, tb+4);
            int s5 = __shfl(idx, tb+5);
            int s6 = __shfl(idx, tb+6);
            int s7 = __shfl(idx, tb+7);
            uint4 u0 = *(const uint4*)(yb + (((unsigned)s0<<8) + lofs));
            uint4 u1 = *(const uint4*)(yb + (((unsigned)s1<<8) + lofs));
            uint4 u2 = *(const uint4*)(yb + (((unsigned)s2<<8) + lofs));
            uint4 u3 = *(const uint4*)(yb + (((unsigned)s3<<8) + lofs));
            uint4 u4 = *(const uint4*)(yb + (((unsigned)s4<<8) + lofs));
            uint4 u5 = *(const uint4*)(yb + (((unsigned)s5<<8) + lofs));
            uint4 u6 = *(const uint4*)(yb + (((unsigned)s6<<8) + lofs));
            uint4 u7 = *(const uint4*)(yb + (((unsigned)s7<<8) + lofs));
            a0 = __hadd2(a0, *(__half2*)&u0.x); a1 = __hadd2(a1, *(__half2*)&u0.y);
            a2 = __hadd2(a2, *(__half2*)&u0.z); a3 = __hadd2(a3, *(__half2*)&u0.w);
            a0 = __hadd2(a0, *(__half2*)&u1.x); a1 = __hadd2(a1, *(__half2*)&u1.y);
            a2 = __hadd2(a2, *(__half2*)&u1.z); a3 = __hadd2(a3, *(__half2*)&u1.w);
            a0 = __hadd2(a0, *(__half2*)&u2.x); a1 = __hadd2(a1, *(__half2*)&u2.y);
            a2 = __hadd2(a2, *(__half2*)&u2.z); a3 = __hadd2(a3, *(__half2*)&u2.w);
            a0 = __hadd2(a0, *(__half2*)&u3.x); a1 = __hadd2(a1, *(__half2*)&u3.y);
            a2 = __hadd2(a2, *(__half2*)&u3.z); a3 = __hadd2(a3, *(__half2*)&u3.w);
            a0 = __hadd2(a0, *(__half2*)&u4.x); a1 = __hadd2(a1, *(__half2*)&u4.y);
            a2 = __hadd2(a2, *(__half2*)&u4.z); a3 = __hadd2(a3, *(__half2*)&u4.w);
            a0 = __hadd2(a0, *(__half2*)&u5.x); a1 = __hadd2(a1, *(__half2*)&u5.y);
            a2 = __hadd2(a2, *(__half2*)&u5.z); a3 = __hadd2(a3, *(__half2*)&u5.w);
            a0 = __hadd2(a0, *(__half2*)&u6.x); a1 = __hadd2(a1, *(__half2*)&u6.y);
            a2 = __hadd2(a2, *(__half2*)&u6.z); a3 = __hadd2(a3, *(__half2*)&u6.w);
            a0 = __hadd2(a0, *(__half2*)&u7.x); a1 = __hadd2(a1, *(__half2*)&u7.y);
            a2 = __hadd2(a2, *(__half2*)&u7.z); a3 = __hadd2(a3, *(__half2*)&u7.w);
        }
        float2 t0 = __half22float2(a0); f0 += t0.x; f1 += t0.y;
        float2 t1 = __half22float2(a1); f2 += t1.x; f3 += t1.y;
        float2 t2 = __half22float2(a2); f4 += t2.x; f5 += t2.y;
        float2 t3 = __half22float2(a3); f6 += t3.x; f7 += t3.y;
    }
    f0 += __shfl_xor(f0,16); f1 += __shfl_xor(f1,16); f2 += __shfl_xor(f2,16); f3 += __shfl_xor(f3,16);
    f4 += __shfl_xor(f4,16); f5 += __shfl_xor(f5,16); f6 += __shfl_xor(f6,16); f7 += __shfl_xor(f7,16);
    f0 += __shfl_xor(f0,32); f1 += __shfl_xor(f1,32); f2 += __shfl_xor(f2,32); f3 += __shfl_xor(f3,32);
    f4 += __shfl_xor(f4,32); f5 += __shfl_xor(f5,32); f6 += __shfl_xor(f6,32); f7 += __shfl_xor(f7,32);
    if (q == 0){
        uint4 su = *(const uint4*)(yb + (((unsigned)wid<<8) + lofs));   // self loop
        float2 s0 = __half22float2(*(__half2*)&su.x); f0 += s0.x; f1 += s0.y;
        float2 s1 = __half22float2(*(__half2*)&su.y); f2 += s1.x; f3 += s1.y;
        float2 s2 = __half22float2(*(__half2*)&su.z); f4 += s2.x; f5 += s2.y;
        float2 s3 = __half22float2(*(__half2*)&su.w); f6 += s3.x; f7 += s3.y;
        float dv = dinv[wid];
        float4 ba = ld4(&b1[ql*8]), bb = ld4(&b1[ql*8+4]);
        float o0 = dv*f0+ba.x, o1 = dv*f1+ba.y, o2 = dv*f2+ba.z, o3 = dv*f3+ba.w;
        float o4 = dv*f4+bb.x, o5 = dv*f5+bb.y, o6 = dv*f6+bb.z, o7 = dv*f7+bb.w;
        o0 = o0>0.f?o0:expm1f(o0); o1 = o1>0.f?o1:expm1f(o1);
        o2 = o2>0.f?o2:expm1f(o2); o3 = o3>0.f?o3:expm1f(o3);
        o4 = o4>0.f?o4:expm1f(o4); o5 = o5>0.f?o5:expm1f(o5);
        o6 = o6>0.f?o6:expm1f(o6); o7 = o7>0.f?o7:expm1f(o7);
        __half2 p0 = __floats2half2_rn(o0,o1), p1 = __floats2half2_rn(o2,o3);
        __half2 p2 = __floats2half2_rn(o4,o5), p3 = __floats2half2_rn(o6,o7);
        uint4 stv; stv.x=*(unsigned*)&p0; stv.y=*(unsigned*)&p1; stv.z=*(unsigned*)&p2; stv.w=*(unsigned*)&p3;
        *reinterpret_cast<uint4*>(&h[(size_t)wid*128 + ql*8]) = stv;
    }
}

// ---------------- mean-pool partial sums (streaming, few atomics) ----------------
__global__ void k_mpoolh(const __half* __restrict__ hsrc, const int* __restrict__ gstart,
                         float* __restrict__ msum){
    int g = blockIdx.x, part = blockIdx.y, P = gridDim.y;
    int c = threadIdx.x;   // 64 threads, half2 cols
    int s0 = gstart[g], s1 = gstart[g+1];
    int len = s1 - s0;
    int per = (len + P - 1) / P;
    int rbeg = s0 + part*per, rend = rbeg + per; if (rend > s1) rend = s1;
    float sx = 0.f, sy = 0.f;
    const __half2* h2 = (const __half2*)hsrc;
    for (int r = rbeg; r < rend; ++r){
        float2 f = __half22float2(h2[(size_t)r*64 + c]);
        sx += f.x; sy += f.y;
    }
    if (rend > rbeg){
        atomicAdd(&msum[g*128 + 2*c], sx);
        atomicAdd(&msum[g*128 + 2*c+1], sy);
    }
}

__global__ void k_mpool(const float* __restrict__ srcm, const int* __restrict__ gstart,
                        float* __restrict__ msum, int C){
    int g = blockIdx.x, part = blockIdx.y, P = gridDim.y;
    int c = threadIdx.x;
    if (c >= C) return;
    int s0 = gstart[g], s1 = gstart[g+1];
    int len = s1 - s0;
    int per = (len + P - 1) / P;
    int rbeg = s0 + part*per, rend = rbeg + per; if (rend > s1) rend = s1;
    float sum = 0.f;
    for (int r = rbeg; r < rend; ++r) sum += srcm[(size_t)r*C + c];
    if (rend > rbeg) atomicAdd(&msum[g*C + c], sum);
}

__global__ void k_mlp1(const float* __restrict__ msum, const int* __restrict__ gstart,
                       const float* __restrict__ mW1, const float* __restrict__ mb1,
                       __half* __restrict__ r1h){
    int g = blockIdx.x, c = threadIdx.x;   // 128 threads
    int cnt = gstart[g+1] - gstart[g];
    float inv = 1.f / (float)(cnt > 1 ? cnt : 1);
    float acc = mb1[c];
    for (int k=0;k<128;k++) acc = fmaf(msum[g*128+k]*inv, mW1[k*128+c], acc);
    r1h[g*128+c] = __float2half(fmaxf(acc, 0.f));
}

__global__ void k_mlp2(const float* __restrict__ msum2, const int* __restrict__ gstart,
                       const float* __restrict__ mW2, const float* __restrict__ mb2,
                       float* __restrict__ r2){
    int g = blockIdx.x, c = threadIdx.x;
    if (c >= 32) return;
    int cnt = gstart[g+1] - gstart[g];
    float inv = 1.f / (float)(cnt > 1 ? cnt : 1);
    float acc = mb2[c];
    for (int k=0;k<32;k++) acc = fmaf(msum2[g*32+k]*inv, mW2[k*32+c], acc);
    r2[g*32+c] = fmaxf(acc, 0.f);
}

// ---------------- GEMM2 (MFMA fp16): y2 = ((h + r1h[batch]) @ W2) * dinv ----------------
__global__ __launch_bounds__(256) void k_gemm2(const __half* __restrict__ h, const __half* __restrict__ r1h,
                                               const int* __restrict__ batch, const __half* __restrict__ w2t,
                                               const float* __restrict__ dinv, __half* __restrict__ y2, int N){
    __shared__ __half Wl[32*136];
    int t = threadIdx.x;
    if (blockIdx.x==0 && t < 8)
        reinterpret_cast<uint2*>(y2 + (size_t)N*32)[t] = make_uint2(0u,0u);
    {
        const uint4* g = (const uint4*)w2t;
        uint4* l = (uint4*)Wl;
        for (int i = t; i < 544; i += 256) l[i] = g[i];
    }
    __syncthreads();
    int wv = t>>6, lane = t&63;
    int r0 = blockIdx.x*64 + wv*16;
    if (r0 >= N) return;
    int lr = lane & 15, lg = lane >> 4;
    int r = r0 + lr;
    bool rok = r < N;
    int rr = rok ? r : 0;
    const __half* hrow = h + (size_t)rr*128;
    const __half* vrow = r1h + (size_t)batch[rr]*128;
    floatx4 acc0 = (floatx4){0.f,0.f,0.f,0.f};
    floatx4 acc1 = (floatx4){0.f,0.f,0.f,0.f};
    #pragma unroll
    for (int ks=0; ks<4; ks++){
        int k0 = ks*32 + lg*8;
        uint4 hu = *reinterpret_cast<const uint4*>(hrow + k0);
        uint4 vu = *reinterpret_cast<const uint4*>(vrow + k0);
        __half2 b0 = __hadd2(*(__half2*)&hu.x, *(__half2*)&vu.x);
        __half2 b1_ = __hadd2(*(__half2*)&hu.y, *(__half2*)&vu.y);
        __half2 b2_ = __hadd2(*(__half2*)&hu.z, *(__half2*)&vu.z);
        __half2 b3_ = __hadd2(*(__half2*)&hu.w, *(__half2*)&vu.w);
        uint4 bu; bu.x=*(unsigned*)&b0; bu.y=*(unsigned*)&b1_; bu.z=*(unsigned*)&b2_; bu.w=*(unsigned*)&b3_;
        half8 bfrag = *reinterpret_cast<half8*>(&bu);
        half8 a0 = *reinterpret_cast<const half8*>(&Wl[(0*16 + lr)*136 + k0]);
        half8 a1 = *reinterpret_cast<const half8*>(&Wl[(1*16 + lr)*136 + k0]);
        acc0 = __builtin_amdgcn_mfma_f32_16x16x32_f16(a0, bfrag, acc0, 0, 0, 0);
        acc1 = __builtin_amdgcn_mfma_f32_16x16x32_f16(a1, bfrag, acc1, 0, 0, 0);
    }
    if (rok){
        float dv = dinv[r];
        {
            __half2 p0 = __floats2half2_rn(acc0[0]*dv, acc0[1]*dv);
            __half2 p1 = __floats2half2_rn(acc0[2]*dv, acc0[3]*dv);
            uint2 stv; stv.x = *(unsigned*)&p0; stv.y = *(unsigned*)&p1;
            *reinterpret_cast<uint2*>(&y2[(size_t)r*32 + 0 + lg*4]) = stv;
        }
        {
            __half2 p0 = __floats2half2_rn(acc1[0]*dv, acc1[1]*dv);
            __half2 p1 = __floats2half2_rn(acc1[2]*dv, acc1[3]*dv);
            uint2 stv; stv.x = *(unsigned*)&p0; stv.y = *(unsigned*)&p1;
            *reinterpret_cast<uint2*>(&y2[(size_t)r*32 + 16 + lg*4]) = stv;
        }
    }
}

// ---------------- layer-2 aggregation: octet-wave 8B gathers, stride-8 split (tile-phased) ----------------
__global__ void k_agg2h(const __half* __restrict__ y2, const float* __restrict__ dinv,
                        const float* __restrict__ b2, const int2* __restrict__ rs2,
                        const unsigned short* __restrict__ csr, float* __restrict__ Z, int N){
    int wid = (int)((blockIdx.x*blockDim.x + threadIdx.x) >> 6);
    if (wid >= N) return;
    int lane = threadIdx.x & 63;
    int o8 = lane >> 3, ol = lane & 7;
    int2 se = rs2[wid];
    int beg = se.x, end = se.y, len = end-beg;
    int olen = (len + 7) >> 3;
    const char* yb = (const char*)y2;
    unsigned lofs = (unsigned)ol * 8u;
    float f0=0.f, f1=0.f, f2=0.f, f3=0.f;
    int iters = (olen + 7) >> 3;
    for (int c=0;c<iters;c++){
        int o = c*8 + ol;
        int j = (o<<3) + o8;                           // stride-8 interleave
        int idx = (j < len) ? (int)csr[beg + j] : N;
        int tb = o8<<3;
        int s0 = __shfl(idx, tb+0);
        int s1 = __shfl(idx, tb+1);
        int s2 = __shfl(idx, tb+2);
        int s3 = __shfl(idx, tb+3);
        int s4 = __shfl(idx, tb+4);
        int s5 = __shfl(idx, tb+5);
        int s6 = __shfl(idx, tb+6);
        int s7 = __shfl(idx, tb+7);
        uint2 u0 = *(const uint2*)(yb + (((unsigned)s0<<6) + lofs));
        uint2 u1 = *(const uint2*)(yb + (((unsigned)s1<<6) + lofs));
        uint2 u2 = *(const uint2*)(yb + (((unsigned)s2<<6) + lofs));
        uint2 u3 = *(const uint2*)(yb + (((unsigned)s3<<6) + lofs));
        uint2 u4 = *(const uint2*)(yb + (((unsigned)s4<<6) + lofs));
        uint2 u5 = *(const uint2*)(yb + (((unsigned)s5<<6) + lofs));
        uint2 u6 = *(const uint2*)(yb + (((unsigned)s6<<6) + lofs));
        uint2 u7 = *(const uint2*)(yb + (((unsigned)s7<<6) + lofs));
        __half2 a0 = __float2half2_rn(0.f), a1 = a0;
        a0 = __hadd2(a0, *(__half2*)&u0.x); a1 = __hadd2(a1, *(__half2*)&u0.y);
        a0 = __hadd2(a0, *(__half2*)&u1.x); a1 = __hadd2(a1, *(__half2*)&u1.y);
        a0 = __hadd2(a0, *(__half2*)&u2.x); a1 = __hadd2(a1, *(__half2*)&u2.y);
        a0 = __hadd2(a0, *(__half2*)&u3.x); a1 = __hadd2(a1, *(__half2*)&u3.y);
        a0 = __hadd2(a0, *(__half2*)&u4.x); a1 = __hadd2(a1, *(__half2*)&u4.y);
        a0 = __hadd2(a0, *(__half2*)&u5.x); a1 = __hadd2(a1, *(__half2*)&u5.y);
        a0 = __hadd2(a0, *(__half2*)&u6.x); a1 = __hadd2(a1, *(__half2*)&u6.y);
        a0 = __hadd2(a0, *(__half2*)&u7.x); a1 = __hadd2(a1, *(__half2*)&u7.y);
        float2 t0 = __half22float2(a0); f0 += t0.x; f1 += t0.y;
        float2 t1 = __half22float2(a1); f2 += t1.x; f3 += t1.y;
    }
    f0 += __shfl_xor(f0,8);  f1 += __shfl_xor(f1,8);  f2 += __shfl_xor(f2,8);  f3 += __shfl_xor(f3,8);
    f0 += __shfl_xor(f0,16); f1 += __shfl_xor(f1,16); f2 += __shfl_xor(f2,16); f3 += __shfl_xor(f3,16);
    f0 += __shfl_xor(f0,32); f1 += __shfl_xor(f1,32); f2 += __shfl_xor(f2,32); f3 += __shfl_xor(f3,32);
    if (o8 == 0){
        uint2 su = *(const uint2*)(yb + (((unsigned)wid<<6) + lofs));   // self loop
        float2 s0 = __half22float2(*(__half2*)&su.x); f0 += s0.x; f1 += s0.y;
        float2 s1 = __half22float2(*(__half2*)&su.y); f2 += s1.x; f3 += s1.y;
        float dv = dinv[wid];
        float4 bb = ld4(&b2[ol*4]);
        float4 outv;
        outv.x = dv*f0 + bb.x; outv.y = dv*f1 + bb.y;
        outv.z = dv*f2 + bb.z; outv.w = dv*f3 + bb.w;
        *reinterpret_cast<float4*>(&Z[(size_t)wid*32 + ol*4]) = outv;
    }
}

// ---------------- + virtual node + softmax (in-place on d_out) ----------------
__global__ void k_softmax(float* __restrict__ Z, const float* __restrict__ r2,
                          const int* __restrict__ batch, int N){
    int r = blockIdx.x*8 + (threadIdx.x>>5);
    int c = threadIdx.x & 31;
    if (r >= N) return;
    float z = Z[(size_t)r*32+c] + r2[batch[r]*32 + c];
    float m = z;
    #pragma unroll
    for (int off=16; off>=1; off>>=1) m = fmaxf(m, __shfl_xor(m, off));
    float e = expf(z - m);
    float s = e;
    #pragma unroll
    for (int off=16; off>=1; off>>=1) s += __shfl_xor(s, off);
    Z[(size_t)r*32+c] = e / s;
}

extern "C" void kernel_launch(void* const* d_in, const int* in_sizes, int n_in,
                              void* d_out, int out_size, void* d_ws, size_t ws_size,
                              hipStream_t stream){
    const float* X   = (const float*)d_in[0];
    const float* W1  = (const float*)d_in[1];
    const float* b1  = (const float*)d_in[2];
    const float* W2  = (const float*)d_in[3];
    const float* b2  = (const float*)d_in[4];
    const float* mW1 = (const float*)d_in[5];
    const float* mb1 = (const float*)d_in[6];
    const float* mW2 = (const float*)d_in[7];
    const float* mb2 = (const float*)d_in[8];
    const int*   ei  = (const int*)d_in[9];
    const int*   batch = (const int*)d_in[10];
    int N = in_sizes[0] / 128;
    int E = in_sizes[9] / 2;
    const int* src = ei;
    const int* dst = ei + E;
    float* Zout = (float*)d_out;

    char* wsp = (char*)d_ws;
    size_t off = 0;
    auto alloc = [&](size_t bytes)->char*{
        char* p = wsp + off; off += (bytes + 255) & ~(size_t)255; return p;
    };
    // zero zone
    int*   bfill = (int*)  alloc((size_t)MAXNB*4);
    float* msum  = (float*)alloc((size_t)GNUM*128*4);
    float* msum2 = (float*)alloc((size_t)GNUM*32*4);
    size_t zero_bytes = off;
    // rest
    int NB = (N + 127) >> 7;            // 391
    int2*  rs2   = (int2*) alloc((size_t)N*8);
    int*   gstart= (int*)  alloc((GNUM+1)*4);
    unsigned* ebuf = (unsigned*)alloc((size_t)NB*CAP*4);
    unsigned short* csr = (unsigned short*)alloc((size_t)NB*CAP*2);
    float* dinvp = (float*)alloc((size_t)N*4);
    __half* w1t  = (__half*)alloc((size_t)W1T_ELEMS*2);
    __half* w2t  = (__half*)alloc((size_t)W2T_ELEMS*2);
    __half* yh   = (__half*)alloc((size_t)(N+1)*128*2);   // +1: zero row
    __half* h    = (__half*)alloc((size_t)N*128*2);
    __half* y2h  = (__half*)alloc((size_t)(N+1)*32*2);    // +1: zero row
    __half* r1buf= (__half*)alloc((size_t)GNUM*128*2);
    float* r2buf = (float*)alloc((size_t)GNUM*32*4);
    (void)ws_size; (void)n_in; (void)out_size;

    hipMemsetAsync(d_ws, 0, zero_bytes, stream);

    int EB = (E + CHUNK-1) / CHUNK;     // 391
    int PREP = (W1T_ELEMS + W2T_ELEMS + 255)/256;   // 85
    int TS = (N + 3)/4;                 // 12500

    k_scatter      <<<EB + PREP, 256, 0, stream>>>(src, dst, E, NB, bfill, ebuf, W1, W2, w1t, w2t, EB);
    k_bucket_finish<<<NB, 256, 0, stream>>>(ebuf, bfill, rs2, csr, dinvp, batch, gstart, N, TS);

    k_gemm1 <<<(N+63)/64, 256, 0, stream>>>(X, w1t, dinvp, yh, N);
    k_agg1  <<<(N+3)/4, 256, 0, stream>>>(yh, dinvp, b1, rs2, csr, h, N);

    k_mpoolh<<<dim3(GNUM,8), 64, 0, stream>>>(h, gstart, msum);
    k_mlp1  <<<GNUM, 128, 0, stream>>>(msum, gstart, mW1, mb1, r1buf);

    k_gemm2 <<<(N+63)/64, 256, 0, stream>>>(h, r1buf, batch, w2t, dinvp, y2h, N);
    k_agg2h <<<(N+3)/4, 256, 0, stream>>>(y2h, dinvp, b2, rs2, csr, Zout, N);

    k_mpool <<<dim3(GNUM,8), 64, 0, stream>>>(Zout, gstart, msum2, 32);
    k_mlp2  <<<GNUM, 64, 0, stream>>>(msum2, gstart, mW2, mb2, r2buf);
    k_softmax<<<(N+7)/8, 256, 0, stream>>>(Zout, r2buf, batch, N);
}